// Round 8
// baseline (1165.569 us; speedup 1.0000x reference)
//
#include <hip/hip_runtime.h>
#include <cstdint>

constexpr int Bn = 128, Tn = 1024, Dn = 64, Hn = 256, On = 128;

typedef __fp16 h2 __attribute__((ext_vector_type(2)));
typedef unsigned short u16;

__device__ __forceinline__ float fast_tanh(float x) {
  float e = __expf(2.0f * x);
  return 1.0f - 2.0f / (e + 1.0f);
}

// v_dot2_f32_f16: 2 f16 MACs with f32 accumulate, full VALU rate.
__device__ __forceinline__ float fdot2(h2 a, h2 b, float c) {
#if __has_builtin(__builtin_amdgcn_fdot2)
  return __builtin_amdgcn_fdot2(a, b, c, false);
#else
  return fmaf((float)a.y, (float)b.y, fmaf((float)a.x, (float)b.x, c));
#endif
}

__device__ __forceinline__ h2 pk2(float a, float b) {
  h2 r; r.x = (__fp16)a; r.y = (__fp16)b; return r;
}
__device__ __forceinline__ h2 bits2h(unsigned u) { return __builtin_bit_cast(h2, u); }
__device__ __forceinline__ unsigned h2bits(h2 v) { return __builtin_bit_cast(unsigned, v); }
__device__ __forceinline__ u16 f2hb(float f) {
  __fp16 h = (__fp16)f; return __builtin_bit_cast(u16, h);
}
__device__ __forceinline__ float hb2f(u16 b) {
  return (float)__builtin_bit_cast(__fp16, b);
}
__device__ __forceinline__ void pin16(h2& w) { asm volatile("" : "+v"(w)); }

template <int CTRL>
__device__ __forceinline__ float dpp_add(float v) {
  int s = __builtin_amdgcn_update_dpp(0, __float_as_int(v), CTRL, 0xF, 0xF, true);
  return v + __int_as_float(s);
}
__device__ __forceinline__ float row16_sum(float v) {
  v = dpp_add<0xB1>(v);   // quad_perm xor1
  v = dpp_add<0x4E>(v);   // quad_perm xor2
  v = dpp_add<0x141>(v);  // ROW_HALF_MIRROR == xor4
  v = dpp_add<0x140>(v);  // ROW_MIRROR == xor8
  return v;
}
__device__ __forceinline__ float sel8(int ks, float s0, float s1, float s2,
                                      float s3, float s4, float s5, float s6,
                                      float s7) {
  float u0 = (ks & 1) ? s1 : s0;
  float u1 = (ks & 1) ? s3 : s2;
  float u2 = (ks & 1) ? s5 : s4;
  float u3 = (ks & 1) ? s7 : s6;
  float v0 = (ks & 2) ? u1 : u0;
  float v1 = (ks & 2) ? u3 : u2;
  return (ks & 4) ? v1 : v0;
}

// Full 256-k matvec for one LDS row (stride-320-half layout, 20*ks chunks):
// every lane computes 8 column partials, DPP-reduces over the 16 ks lanes,
// and returns this lane's selected column value (pre-bias).
__device__ __forceinline__ float colval256(const u16* rowbase, int ks,
                                           const h2 (&w)[8][8]) {
  const uint2* hq = (const uint2*)(rowbase + 20 * ks);
  uint2 q0 = hq[0], q1 = hq[1], q2 = hq[2], q3 = hq[3];
  float a0 = 0.f, a1 = 0.f, a2 = 0.f, a3 = 0.f,
        a4 = 0.f, a5 = 0.f, a6 = 0.f, a7 = 0.f;
  const unsigned d[8] = {q0.x, q0.y, q1.x, q1.y, q2.x, q2.y, q3.x, q3.y};
  #pragma unroll
  for (int p = 0; p < 8; ++p) {
    h2 hp = bits2h(d[p]);
    a0 = fdot2(hp, w[p][0], a0);
    a1 = fdot2(hp, w[p][1], a1);
    a2 = fdot2(hp, w[p][2], a2);
    a3 = fdot2(hp, w[p][3], a3);
    a4 = fdot2(hp, w[p][4], a4);
    a5 = fdot2(hp, w[p][5], a5);
    a6 = fdot2(hp, w[p][6], a6);
    a7 = fdot2(hp, w[p][7], a7);
  }
  float s0 = row16_sum(a0), s1 = row16_sum(a1);
  float s2 = row16_sum(a2), s3 = row16_sum(a3);
  float s4 = row16_sum(a4), s5 = row16_sum(a5);
  float s6 = row16_sum(a6), s7 = row16_sum(a7);
  return sel8(ks, s0, s1, s2, s3, s4, s5, s6, s7);
}

// LDS h layout (f16): 16 slices x (16 data + 4 pad) halfs; slice stride 40 B
// -> reader dwords 10*ks mod 32 all distinct, conflict-free; 8 B aligned.
// ---------------------------------------------------------------------------
// Fused pipeline, 256 WGs x 1024 threads == 1 block/CU guaranteed.
// REGISTER DISCIPLINE (round-7 lesson): a 1024-thr block must fit 128
// regs/wave; with only a MINIMUM occupancy hint the allocator targeted
// 8 waves/EU and split 64 arch + 64 AGPR -> v_accvgpr_read on every weight
// use in BOTH roles (VGPR_Count=64, A step 0.76->~1.1us, stage1 1158).
// amdgpu_waves_per_eu(4,4) pins the target to exactly our occupancy
// (16 waves/CU) -> budget exactly 128 -> ~104-reg paths stay in arch VGPRs.
//   role A  (blocks 0..127): waves 8-15 exit immediately (before any
//       barrier); waves 0-7 run the round-0 scan1 producer unchanged.
//   role BC (blocks 128..255): WAVE-SPECIALIZED, barriers in common code.
//       waves 0-7  (512 thr): serial scan2 (Wh2 in their VGPRs).
//       waves 8-15 (512 thr): dense u2 = h1@Wx2+b2 -> LDS (Wx2 in theirs).
//       Per chunk: dense spins flag, stages h1, computes u2 row 0; then 32
//       slices: serial step s || dense u2 row s+1; one barrier per slice.
// ---------------------------------------------------------------------------
__global__ __launch_bounds__(1024)
__attribute__((amdgpu_waves_per_eu(4, 4))) void stage1_kernel(
    const float* __restrict__ x,    // [B,T,64] f32
    const float* __restrict__ Wx1,  // [64,256] f32
    const float* __restrict__ Wh1,  // [256,256] f32
    const float* __restrict__ b1,   // [256]
    const float* __restrict__ Wx2,  // [256,256] f32
    const float* __restrict__ b2,   // [256]
    const float* __restrict__ Wh2,  // [256,256] f32
    u16* __restrict__ h1b16,        // [B,T,256] f16 h1 (A -> BC channel)
    int* __restrict__ flags,        // [B]  A -> BC progress (32-step blocks)
    float* __restrict__ hfinal) {   // [B,256] f32 (role BC output)
  __shared__ alignas(16) u16 smemU[19584];  // 38.25 KB
  const int tid = threadIdx.x;
  const unsigned bid = blockIdx.x;

  // Role-A blocks use only waves 0-7; waves 8-15 exit BEFORE any barrier.
  if (bid < (unsigned)Bn && tid >= 512) return;

  if (bid < (unsigned)Bn) {
    // ================= ROLE A: scan1 producer (waves 0-7) =================
    const int ks = tid & 15;
    const int cg = tid >> 4;
    const int col0 = 8 * cg;
    const int jcol = col0 + (ks & 7);
    const bool writer = (ks < 8);
    const int b = bid;
    const float* xb = x + (size_t)b * Tn * Dn;
    u16* hb = h1b16 + (size_t)b * Tn * Hn;
    u16* hcH = smemU;          // 2 x 320 halfs
    u16* xsH = smemU + 768;    // 2 x 2048 halfs (32-step x blocks, f16)

    h2 wh[8][8];  // Wh1 k-pairs (16ks+2p, +1) x 8 cols
    #pragma unroll
    for (int p = 0; p < 8; ++p) {
      const float* r0 = Wh1 + (size_t)(16 * ks + 2 * p) * Hn + col0;
      float4 a0 = *(const float4*)r0, a1 = *(const float4*)(r0 + 4);
      float4 c0 = *(const float4*)(r0 + Hn), c1 = *(const float4*)(r0 + Hn + 4);
      wh[p][0] = pk2(a0.x, c0.x); wh[p][1] = pk2(a0.y, c0.y);
      wh[p][2] = pk2(a0.z, c0.z); wh[p][3] = pk2(a0.w, c0.w);
      wh[p][4] = pk2(a1.x, c1.x); wh[p][5] = pk2(a1.y, c1.y);
      wh[p][6] = pk2(a1.z, c1.z); wh[p][7] = pk2(a1.w, c1.w);
    }
    h2 wx[2][8];  // Wx1 k-pairs (4ks+2p, +1)
    #pragma unroll
    for (int p = 0; p < 2; ++p) {
      const float* r0 = Wx1 + (size_t)(4 * ks + 2 * p) * Hn + col0;
      float4 a0 = *(const float4*)r0, a1 = *(const float4*)(r0 + 4);
      float4 c0 = *(const float4*)(r0 + Hn), c1 = *(const float4*)(r0 + Hn + 4);
      wx[p][0] = pk2(a0.x, c0.x); wx[p][1] = pk2(a0.y, c0.y);
      wx[p][2] = pk2(a0.z, c0.z); wx[p][3] = pk2(a0.w, c0.w);
      wx[p][4] = pk2(a1.x, c1.x); wx[p][5] = pk2(a1.y, c1.y);
      wx[p][6] = pk2(a1.z, c1.z); wx[p][7] = pk2(a1.w, c1.w);
    }
    #pragma unroll
    for (int p = 0; p < 8; ++p)
      #pragma unroll
      for (int c = 0; c < 8; ++c) pin16(wh[p][c]);
    #pragma unroll
    for (int p = 0; p < 2; ++p)
      #pragma unroll
      for (int c = 0; c < 8; ++c) pin16(wx[p][c]);

    const float bj = b1[jcol];
    const int woffH = 20 * (jcol >> 4) + (jcol & 15);

    for (int i = tid; i < 640; i += 512) hcH[i] = 0;  // zero both h buffers
    {
      float4 x0 = *(const float4*)(xb + 4 * tid);  // block 0 -> f16 LDS
      ((uint2*)xsH)[tid] = make_uint2(h2bits(pk2(x0.x, x0.y)), h2bits(pk2(x0.z, x0.w)));
    }
    __syncthreads();

    u16 hreg[8];
    float4 xr = make_float4(0.f, 0.f, 0.f, 0.f);
    for (int t8 = 0; t8 < 128; ++t8) {
      const int xcur = (t8 >> 2) & 1;
      #pragma unroll
      for (int s = 0; s < 8; ++s) {
        const int t = t8 * 8 + s;
        const int cu = s & 1, nx = cu ^ 1;
        if (s == 0 && (t8 & 3) == 0 && t8 < 124)
          xr = *(const float4*)(xb + (size_t)((t8 >> 2) + 1) * 2048 + 4 * tid);

        const uint2* hq = (const uint2*)(hcH + cu * 320 + 20 * ks);
        uint2 q0 = hq[0], q1 = hq[1], q2 = hq[2], q3 = hq[3];
        uint2 xq = *(const uint2*)(xsH + xcur * 2048 + ((t & 31) << 6) + 4 * ks);
        float a0 = 0.f, a1 = 0.f, a2 = 0.f, a3 = 0.f,
              a4 = 0.f, a5 = 0.f, a6 = 0.f, a7 = 0.f;
        const unsigned d[8] = {q0.x, q0.y, q1.x, q1.y, q2.x, q2.y, q3.x, q3.y};
        #pragma unroll
        for (int p = 0; p < 8; ++p) {
          h2 hp = bits2h(d[p]);
          a0 = fdot2(hp, wh[p][0], a0);
          a1 = fdot2(hp, wh[p][1], a1);
          a2 = fdot2(hp, wh[p][2], a2);
          a3 = fdot2(hp, wh[p][3], a3);
          a4 = fdot2(hp, wh[p][4], a4);
          a5 = fdot2(hp, wh[p][5], a5);
          a6 = fdot2(hp, wh[p][6], a6);
          a7 = fdot2(hp, wh[p][7], a7);
        }
        {
          h2 xp0 = bits2h(xq.x), xp1 = bits2h(xq.y);
          a0 = fdot2(xp0, wx[0][0], a0); a0 = fdot2(xp1, wx[1][0], a0);
          a1 = fdot2(xp0, wx[0][1], a1); a1 = fdot2(xp1, wx[1][1], a1);
          a2 = fdot2(xp0, wx[0][2], a2); a2 = fdot2(xp1, wx[1][2], a2);
          a3 = fdot2(xp0, wx[0][3], a3); a3 = fdot2(xp1, wx[1][3], a3);
          a4 = fdot2(xp0, wx[0][4], a4); a4 = fdot2(xp1, wx[1][4], a4);
          a5 = fdot2(xp0, wx[0][5], a5); a5 = fdot2(xp1, wx[1][5], a5);
          a6 = fdot2(xp0, wx[0][6], a6); a6 = fdot2(xp1, wx[1][6], a6);
          a7 = fdot2(xp0, wx[0][7], a7); a7 = fdot2(xp1, wx[1][7], a7);
        }
        float s0 = row16_sum(a0), s1 = row16_sum(a1);
        float s2 = row16_sum(a2), s3 = row16_sum(a3);
        float s4 = row16_sum(a4), s5 = row16_sum(a5);
        float s6 = row16_sum(a6), s7 = row16_sum(a7);
        float h = fast_tanh(sel8(ks, s0, s1, s2, s3, s4, s5, s6, s7) + bj);
        u16 hbits = f2hb(h);
        if (writer) hcH[nx * 320 + woffH] = hbits;
        hreg[s] = hbits;
        if (s == 7) {
          if (writer) {
            u16* dst = hb + (size_t)(t - 7) * Hn + jcol;
            #pragma unroll
            for (int i = 0; i < 8; ++i) dst[i * Hn] = hreg[i];
          }
          if ((t8 & 3) == 3 && t8 < 127)
            ((uint2*)(xsH + (xcur ^ 1) * 2048))[tid] =
                make_uint2(h2bits(pk2(xr.x, xr.y)), h2bits(pk2(xr.z, xr.w)));
        }
        __syncthreads();  // vmcnt(0) drained -> safe to release
        if (s == 7 && (t8 & 3) == 3 && tid == 0)
          __hip_atomic_store(flags + bid, (t8 >> 2) + 1, __ATOMIC_RELEASE,
                             __HIP_MEMORY_SCOPE_AGENT);
      }
    }
  } else {
    // ========== ROLE BC: wave-specialized serial scan2 || dense u2 ========
    const int b = bid - Bn;
    const u16* hb1 = h1b16 + (size_t)b * Tn * Hn;
    u16* hsH = smemU;            // [32][320] halfs = 20 KB (h1 staging)
    u16* u2S = smemU + 10240;    // [32][272] halfs = 17 KB (u2 buffer)
    u16* hcU = smemU + 18944;    // 2 x 320 halfs (h2 state)

    const bool serialG = (tid < 512);
    const int lt = tid & 511;
    const int ks = lt & 15;
    const int cg = lt >> 4;
    const int col0 = 8 * cg;
    const int jcol = col0 + (ks & 7);
    const bool writer = (ks < 8);
    const int woffH = 20 * (jcol >> 4) + (jcol & 15);

    // Wave-divergent weight source: serial waves hold Wh2, dense waves Wx2.
    const float* Wsrc = serialG ? Wh2 : Wx2;
    h2 w[8][8];
    #pragma unroll
    for (int p = 0; p < 8; ++p) {
      const float* r0 = Wsrc + (size_t)(16 * ks + 2 * p) * Hn + col0;
      float4 a0 = *(const float4*)r0, a1 = *(const float4*)(r0 + 4);
      float4 c0 = *(const float4*)(r0 + Hn), c1 = *(const float4*)(r0 + Hn + 4);
      w[p][0] = pk2(a0.x, c0.x); w[p][1] = pk2(a0.y, c0.y);
      w[p][2] = pk2(a0.z, c0.z); w[p][3] = pk2(a0.w, c0.w);
      w[p][4] = pk2(a1.x, c1.x); w[p][5] = pk2(a1.y, c1.y);
      w[p][6] = pk2(a1.z, c1.z); w[p][7] = pk2(a1.w, c1.w);
    }
    #pragma unroll
    for (int p = 0; p < 8; ++p)
      #pragma unroll
      for (int c = 0; c < 8; ++c) pin16(w[p][c]);

    const float b2j = b2[jcol];  // used by dense waves only

    // Staging coords (dense waves)
    const int lr = lt >> 4;   // step row within chunk (0..31)
    const int lc = lt & 15;   // 16-half column chunk
    u16* ldst = hsH + lr * 320 + 20 * lc;

    if (serialG)
      for (int i = lt; i < 640; i += 512) hcU[i] = 0;  // zero h2 state
    __syncthreads();

    for (int blk = 0; blk < 32; ++blk) {
      // --- pre-phase: dense waves acquire h1 chunk & seed u2 row 0 ---
      if (!serialG && lt == 0) {
        while (__hip_atomic_load(flags + b, __ATOMIC_ACQUIRE,
                                 __HIP_MEMORY_SCOPE_AGENT) < blk + 1)
          __builtin_amdgcn_s_sleep(8);
      }
      __syncthreads();  // B1: flag acquired for all
      if (!serialG) {   // stage h1 chunk [32 steps][256] -> hsH
        const uint4* src =
            (const uint4*)(hb1 + (size_t)(blk * 32 + lr) * Hn + 16 * lc);
        uint4 v0 = src[0], v1 = src[1];  // 32 B = 16 halfs
        ((uint2*)ldst)[0] = make_uint2(v0.x, v0.y);
        ((uint2*)ldst)[1] = make_uint2(v0.z, v0.w);
        ((uint2*)ldst)[2] = make_uint2(v1.x, v1.y);
        ((uint2*)ldst)[3] = make_uint2(v1.z, v1.w);
      }
      __syncthreads();  // B2: staging visible
      if (!serialG) {   // u2 row 0
        float v = colval256(hsH, ks, w);
        if (writer) u2S[jcol] = f2hb(v + b2j);
      }
      __syncthreads();  // B3: row 0 visible

      // --- 32 slices: serial step s || dense u2 row s+1 ---
      for (int g = 0; g < 4; ++g) {
        #pragma unroll
        for (int s8 = 0; s8 < 8; ++s8) {
          const int s = g * 8 + s8;
          if (serialG) {
            const int cu = s & 1, nx = cu ^ 1;
            float uval = hb2f(u2S[s * 272 + jcol]);
            float acc = colval256(hcU + cu * 320, ks, w);
            float h = fast_tanh(acc + uval);
            if (writer) hcU[nx * 320 + woffH] = f2hb(h);
          } else if (s < 31) {
            float v = colval256(hsH + (s + 1) * 320, ks, w);
            if (writer) u2S[(s + 1) * 272 + jcol] = f2hb(v + b2j);
          }
          __syncthreads();
        }
      }
    }
    if (tid < Hn)
      hfinal[(size_t)b * Hn + tid] = hb2f(hcU[(tid >> 4) * 20 + (tid & 15)]);
  }
}

// ---------------------------------------------------------------------------
// Head: out = softmax(h2_T @ Wd + bd). f32, unchanged.
// ---------------------------------------------------------------------------
__global__ __launch_bounds__(128) void head_kernel(
    const float* __restrict__ hfinal, const float* __restrict__ Wd,
    const float* __restrict__ bd, float* __restrict__ out) {
  __shared__ float hrow[Hn];
  __shared__ float red[On];
  const int o = threadIdx.x;
  const int b = blockIdx.x;
  hrow[o] = hfinal[(size_t)b * Hn + o];
  hrow[o + 128] = hfinal[(size_t)b * Hn + 128 + o];
  __syncthreads();
  float acc = bd[o];
  #pragma unroll 8
  for (int k = 0; k < Hn; ++k) acc = fmaf(hrow[k], Wd[(size_t)k * On + o], acc);
  red[o] = acc;
  __syncthreads();
  #pragma unroll
  for (int s = 64; s > 0; s >>= 1) {
    if (o < s) red[o] = fmaxf(red[o], red[o + s]);
    __syncthreads();
  }
  const float mx = red[0];
  __syncthreads();
  const float e = __expf(acc - mx);
  red[o] = e;
  __syncthreads();
  #pragma unroll
  for (int s = 64; s > 0; s >>= 1) {
    if (o < s) red[o] += red[o + s];
    __syncthreads();
  }
  out[(size_t)b * On + o] = e / red[0];
}

// ---------------------------------------------------------------------------
extern "C" void kernel_launch(void* const* d_in, const int* in_sizes, int n_in,
                              void* d_out, int out_size, void* d_ws, size_t ws_size,
                              hipStream_t stream) {
  const float* x   = (const float*)d_in[0];
  const float* Wx1 = (const float*)d_in[1];
  const float* Wh1 = (const float*)d_in[2];
  const float* b1  = (const float*)d_in[3];
  const float* Wx2 = (const float*)d_in[4];
  const float* Wh2 = (const float*)d_in[5];
  const float* b2  = (const float*)d_in[6];
  const float* Wd  = (const float*)d_in[7];
  const float* bd  = (const float*)d_in[8];
  float* out = (float*)d_out;

  u16* h1b16 = (u16*)d_ws;                            // [B,T,256] f16 (64 MB)
  float* hfinal = (float*)(h1b16 + (size_t)Bn * Tn * Hn);  // [B,256] f32
  int* flags = (int*)(hfinal + (size_t)Bn * Hn);      // [B] A->BC

  hipMemsetAsync(flags, 0, Bn * sizeof(int), stream);
  stage1_kernel<<<2 * Bn, 1024, 0, stream>>>(x, Wx1, Wh1, b1, Wx2, b2, Wh2,
                                             h1b16, flags, hfinal);
  head_kernel<<<Bn, 128, 0, stream>>>(hfinal, Wd, bd, out);
}

// Round 9
// 1152.649 us; speedup vs baseline: 1.0112x; 1.0112x over previous
//
#include <hip/hip_runtime.h>
#include <cstdint>

constexpr int Bn = 128, Tn = 1024, Dn = 64, Hn = 256, On = 128;

typedef __fp16 h2 __attribute__((ext_vector_type(2)));
typedef unsigned short u16;

__device__ __forceinline__ float fast_tanh(float x) {
  float e = __expf(2.0f * x);
  return 1.0f - 2.0f / (e + 1.0f);
}

// v_dot2_f32_f16: 2 f16 MACs with f32 accumulate, full VALU rate.
__device__ __forceinline__ float fdot2(h2 a, h2 b, float c) {
#if __has_builtin(__builtin_amdgcn_fdot2)
  return __builtin_amdgcn_fdot2(a, b, c, false);
#else
  return fmaf((float)a.y, (float)b.y, fmaf((float)a.x, (float)b.x, c));
#endif
}

__device__ __forceinline__ h2 pk2(float a, float b) {
  h2 r; r.x = (__fp16)a; r.y = (__fp16)b; return r;
}
__device__ __forceinline__ h2 bits2h(unsigned u) { return __builtin_bit_cast(h2, u); }
__device__ __forceinline__ unsigned h2bits(h2 v) { return __builtin_bit_cast(unsigned, v); }
__device__ __forceinline__ u16 f2hb(float f) {
  __fp16 h = (__fp16)f; return __builtin_bit_cast(u16, h);
}
__device__ __forceinline__ float hb2f(u16 b) {
  return (float)__builtin_bit_cast(__fp16, b);
}
// NOTE: NO inline asm anywhere in stage1_kernel. Round-8 finding: any inline
// asm (the old pin16/pinA "+v"/"+a" pins) makes LLVM's unified-RF code flag
// the function as may-need-AGPRs, which caps ARCH VGPRs at HALF the
// occupancy budget (observed: VGPR_Count=64 of 128, =128 of 256 across
// rounds 2/7/8). The pins meant to keep weights in arch VGPRs were the very
// thing evicting them to AGPRs. With no asm, the full 128-reg budget is
// architectural and the ~120-reg per-thread demand fits cleanly.

template <int CTRL>
__device__ __forceinline__ float dpp_add(float v) {
  int s = __builtin_amdgcn_update_dpp(0, __float_as_int(v), CTRL, 0xF, 0xF, true);
  return v + __int_as_float(s);
}
__device__ __forceinline__ float row16_sum(float v) {
  v = dpp_add<0xB1>(v);   // quad_perm xor1
  v = dpp_add<0x4E>(v);   // quad_perm xor2
  v = dpp_add<0x141>(v);  // ROW_HALF_MIRROR == xor4
  v = dpp_add<0x140>(v);  // ROW_MIRROR == xor8
  return v;
}
__device__ __forceinline__ float sel8(int ks, float s0, float s1, float s2,
                                      float s3, float s4, float s5, float s6,
                                      float s7) {
  float u0 = (ks & 1) ? s1 : s0;
  float u1 = (ks & 1) ? s3 : s2;
  float u2 = (ks & 1) ? s5 : s4;
  float u3 = (ks & 1) ? s7 : s6;
  float v0 = (ks & 2) ? u1 : u0;
  float v1 = (ks & 2) ? u3 : u2;
  return (ks & 4) ? v1 : v0;
}

// Full 256-k matvec for one LDS row (stride-320-half layout, 20*ks chunks):
// every lane computes 8 column partials, DPP-reduces over the 16 ks lanes,
// and returns this lane's selected column value (pre-bias).
__device__ __forceinline__ float colval256(const u16* rowbase, int ks,
                                           const h2 (&w)[8][8]) {
  const uint2* hq = (const uint2*)(rowbase + 20 * ks);
  uint2 q0 = hq[0], q1 = hq[1], q2 = hq[2], q3 = hq[3];
  float a0 = 0.f, a1 = 0.f, a2 = 0.f, a3 = 0.f,
        a4 = 0.f, a5 = 0.f, a6 = 0.f, a7 = 0.f;
  const unsigned d[8] = {q0.x, q0.y, q1.x, q1.y, q2.x, q2.y, q3.x, q3.y};
  #pragma unroll
  for (int p = 0; p < 8; ++p) {
    h2 hp = bits2h(d[p]);
    a0 = fdot2(hp, w[p][0], a0);
    a1 = fdot2(hp, w[p][1], a1);
    a2 = fdot2(hp, w[p][2], a2);
    a3 = fdot2(hp, w[p][3], a3);
    a4 = fdot2(hp, w[p][4], a4);
    a5 = fdot2(hp, w[p][5], a5);
    a6 = fdot2(hp, w[p][6], a6);
    a7 = fdot2(hp, w[p][7], a7);
  }
  float s0 = row16_sum(a0), s1 = row16_sum(a1);
  float s2 = row16_sum(a2), s3 = row16_sum(a3);
  float s4 = row16_sum(a4), s5 = row16_sum(a5);
  float s6 = row16_sum(a6), s7 = row16_sum(a7);
  return sel8(ks, s0, s1, s2, s3, s4, s5, s6, s7);
}

// LDS h layout (f16): 16 slices x (16 data + 4 pad) halfs; slice stride 40 B
// -> reader dwords 10*ks mod 32 all distinct, conflict-free; 8 B aligned.
// ---------------------------------------------------------------------------
// Fused pipeline, 256 WGs x 1024 threads == 1 block/CU guaranteed.
// waves_per_eu(4,4): pin the allocator's occupancy target to exactly our
// 16-wave block (4 waves/EU) -> 128-reg budget. Combined with the no-asm
// rule above, the full budget is architectural.
//   role A  (blocks 0..127): waves 8-15 exit immediately (before any
//       barrier); waves 0-7 run the round-0 scan1 producer unchanged.
//   role BC (blocks 128..255): WAVE-SPECIALIZED, barriers in common code.
//       waves 0-7  (512 thr): serial scan2 (Wh2 in their VGPRs).
//       waves 8-15 (512 thr): dense u2 = h1@Wx2+b2 -> LDS (Wx2 in theirs).
//       Per chunk: dense spins flag, stages h1, computes u2 row 0; then 32
//       slices: serial step s || dense u2 row s+1; one barrier per slice.
//       (Same-thread fusion of these two phases costs ~40us/chunk — rounds
//       2/4/5; separate waves co-schedule at ~max, not sum — m114.)
// ---------------------------------------------------------------------------
__global__ __launch_bounds__(1024)
__attribute__((amdgpu_waves_per_eu(4, 4))) void stage1_kernel(
    const float* __restrict__ x,    // [B,T,64] f32
    const float* __restrict__ Wx1,  // [64,256] f32
    const float* __restrict__ Wh1,  // [256,256] f32
    const float* __restrict__ b1,   // [256]
    const float* __restrict__ Wx2,  // [256,256] f32
    const float* __restrict__ b2,   // [256]
    const float* __restrict__ Wh2,  // [256,256] f32
    u16* __restrict__ h1b16,        // [B,T,256] f16 h1 (A -> BC channel)
    int* __restrict__ flags,        // [B]  A -> BC progress (32-step blocks)
    float* __restrict__ hfinal) {   // [B,256] f32 (role BC output)
  __shared__ alignas(16) u16 smemU[19584];  // 38.25 KB
  const int tid = threadIdx.x;
  const unsigned bid = blockIdx.x;

  // Role-A blocks use only waves 0-7; waves 8-15 exit BEFORE any barrier.
  if (bid < (unsigned)Bn && tid >= 512) return;

  if (bid < (unsigned)Bn) {
    // ================= ROLE A: scan1 producer (waves 0-7) =================
    const int ks = tid & 15;
    const int cg = tid >> 4;
    const int col0 = 8 * cg;
    const int jcol = col0 + (ks & 7);
    const bool writer = (ks < 8);
    const int b = bid;
    const float* xb = x + (size_t)b * Tn * Dn;
    u16* hb = h1b16 + (size_t)b * Tn * Hn;
    u16* hcH = smemU;          // 2 x 320 halfs
    u16* xsH = smemU + 768;    // 2 x 2048 halfs (32-step x blocks, f16)

    h2 wh[8][8];  // Wh1 k-pairs (16ks+2p, +1) x 8 cols
    #pragma unroll
    for (int p = 0; p < 8; ++p) {
      const float* r0 = Wh1 + (size_t)(16 * ks + 2 * p) * Hn + col0;
      float4 a0 = *(const float4*)r0, a1 = *(const float4*)(r0 + 4);
      float4 c0 = *(const float4*)(r0 + Hn), c1 = *(const float4*)(r0 + Hn + 4);
      wh[p][0] = pk2(a0.x, c0.x); wh[p][1] = pk2(a0.y, c0.y);
      wh[p][2] = pk2(a0.z, c0.z); wh[p][3] = pk2(a0.w, c0.w);
      wh[p][4] = pk2(a1.x, c1.x); wh[p][5] = pk2(a1.y, c1.y);
      wh[p][6] = pk2(a1.z, c1.z); wh[p][7] = pk2(a1.w, c1.w);
    }
    h2 wx[2][8];  // Wx1 k-pairs (4ks+2p, +1)
    #pragma unroll
    for (int p = 0; p < 2; ++p) {
      const float* r0 = Wx1 + (size_t)(4 * ks + 2 * p) * Hn + col0;
      float4 a0 = *(const float4*)r0, a1 = *(const float4*)(r0 + 4);
      float4 c0 = *(const float4*)(r0 + Hn), c1 = *(const float4*)(r0 + Hn + 4);
      wx[p][0] = pk2(a0.x, c0.x); wx[p][1] = pk2(a0.y, c0.y);
      wx[p][2] = pk2(a0.z, c0.z); wx[p][3] = pk2(a0.w, c0.w);
      wx[p][4] = pk2(a1.x, c1.x); wx[p][5] = pk2(a1.y, c1.y);
      wx[p][6] = pk2(a1.z, c1.z); wx[p][7] = pk2(a1.w, c1.w);
    }

    const float bj = b1[jcol];
    const int woffH = 20 * (jcol >> 4) + (jcol & 15);

    for (int i = tid; i < 640; i += 512) hcH[i] = 0;  // zero both h buffers
    {
      float4 x0 = *(const float4*)(xb + 4 * tid);  // block 0 -> f16 LDS
      ((uint2*)xsH)[tid] = make_uint2(h2bits(pk2(x0.x, x0.y)), h2bits(pk2(x0.z, x0.w)));
    }
    __syncthreads();

    u16 hreg[8];
    float4 xr = make_float4(0.f, 0.f, 0.f, 0.f);
    for (int t8 = 0; t8 < 128; ++t8) {
      const int xcur = (t8 >> 2) & 1;
      #pragma unroll
      for (int s = 0; s < 8; ++s) {
        const int t = t8 * 8 + s;
        const int cu = s & 1, nx = cu ^ 1;
        if (s == 0 && (t8 & 3) == 0 && t8 < 124)
          xr = *(const float4*)(xb + (size_t)((t8 >> 2) + 1) * 2048 + 4 * tid);

        const uint2* hq = (const uint2*)(hcH + cu * 320 + 20 * ks);
        uint2 q0 = hq[0], q1 = hq[1], q2 = hq[2], q3 = hq[3];
        uint2 xq = *(const uint2*)(xsH + xcur * 2048 + ((t & 31) << 6) + 4 * ks);
        float a0 = 0.f, a1 = 0.f, a2 = 0.f, a3 = 0.f,
              a4 = 0.f, a5 = 0.f, a6 = 0.f, a7 = 0.f;
        const unsigned d[8] = {q0.x, q0.y, q1.x, q1.y, q2.x, q2.y, q3.x, q3.y};
        #pragma unroll
        for (int p = 0; p < 8; ++p) {
          h2 hp = bits2h(d[p]);
          a0 = fdot2(hp, wh[p][0], a0);
          a1 = fdot2(hp, wh[p][1], a1);
          a2 = fdot2(hp, wh[p][2], a2);
          a3 = fdot2(hp, wh[p][3], a3);
          a4 = fdot2(hp, wh[p][4], a4);
          a5 = fdot2(hp, wh[p][5], a5);
          a6 = fdot2(hp, wh[p][6], a6);
          a7 = fdot2(hp, wh[p][7], a7);
        }
        {
          h2 xp0 = bits2h(xq.x), xp1 = bits2h(xq.y);
          a0 = fdot2(xp0, wx[0][0], a0); a0 = fdot2(xp1, wx[1][0], a0);
          a1 = fdot2(xp0, wx[0][1], a1); a1 = fdot2(xp1, wx[1][1], a1);
          a2 = fdot2(xp0, wx[0][2], a2); a2 = fdot2(xp1, wx[1][2], a2);
          a3 = fdot2(xp0, wx[0][3], a3); a3 = fdot2(xp1, wx[1][3], a3);
          a4 = fdot2(xp0, wx[0][4], a4); a4 = fdot2(xp1, wx[1][4], a4);
          a5 = fdot2(xp0, wx[0][5], a5); a5 = fdot2(xp1, wx[1][5], a5);
          a6 = fdot2(xp0, wx[0][6], a6); a6 = fdot2(xp1, wx[1][6], a6);
          a7 = fdot2(xp0, wx[0][7], a7); a7 = fdot2(xp1, wx[1][7], a7);
        }
        float s0 = row16_sum(a0), s1 = row16_sum(a1);
        float s2 = row16_sum(a2), s3 = row16_sum(a3);
        float s4 = row16_sum(a4), s5 = row16_sum(a5);
        float s6 = row16_sum(a6), s7 = row16_sum(a7);
        float h = fast_tanh(sel8(ks, s0, s1, s2, s3, s4, s5, s6, s7) + bj);
        u16 hbits = f2hb(h);
        if (writer) hcH[nx * 320 + woffH] = hbits;
        hreg[s] = hbits;
        if (s == 7) {
          if (writer) {
            u16* dst = hb + (size_t)(t - 7) * Hn + jcol;
            #pragma unroll
            for (int i = 0; i < 8; ++i) dst[i * Hn] = hreg[i];
          }
          if ((t8 & 3) == 3 && t8 < 127)
            ((uint2*)(xsH + (xcur ^ 1) * 2048))[tid] =
                make_uint2(h2bits(pk2(xr.x, xr.y)), h2bits(pk2(xr.z, xr.w)));
        }
        __syncthreads();  // vmcnt(0) drained -> safe to release
        if (s == 7 && (t8 & 3) == 3 && tid == 0)
          __hip_atomic_store(flags + bid, (t8 >> 2) + 1, __ATOMIC_RELEASE,
                             __HIP_MEMORY_SCOPE_AGENT);
      }
    }
  } else {
    // ========== ROLE BC: wave-specialized serial scan2 || dense u2 ========
    const int b = bid - Bn;
    const u16* hb1 = h1b16 + (size_t)b * Tn * Hn;
    u16* hsH = smemU;            // [32][320] halfs = 20 KB (h1 staging)
    u16* u2S = smemU + 10240;    // [32][272] halfs = 17 KB (u2 buffer)
    u16* hcU = smemU + 18944;    // 2 x 320 halfs (h2 state)

    const bool serialG = (tid < 512);
    const int lt = tid & 511;
    const int ks = lt & 15;
    const int cg = lt >> 4;
    const int col0 = 8 * cg;
    const int jcol = col0 + (ks & 7);
    const bool writer = (ks < 8);
    const int woffH = 20 * (jcol >> 4) + (jcol & 15);

    // Wave-divergent weight source: serial waves hold Wh2, dense waves Wx2.
    const float* Wsrc = serialG ? Wh2 : Wx2;
    h2 w[8][8];
    #pragma unroll
    for (int p = 0; p < 8; ++p) {
      const float* r0 = Wsrc + (size_t)(16 * ks + 2 * p) * Hn + col0;
      float4 a0 = *(const float4*)r0, a1 = *(const float4*)(r0 + 4);
      float4 c0 = *(const float4*)(r0 + Hn), c1 = *(const float4*)(r0 + Hn + 4);
      w[p][0] = pk2(a0.x, c0.x); w[p][1] = pk2(a0.y, c0.y);
      w[p][2] = pk2(a0.z, c0.z); w[p][3] = pk2(a0.w, c0.w);
      w[p][4] = pk2(a1.x, c1.x); w[p][5] = pk2(a1.y, c1.y);
      w[p][6] = pk2(a1.z, c1.z); w[p][7] = pk2(a1.w, c1.w);
    }

    const float b2j = b2[jcol];  // used by dense waves only

    // Staging coords (dense waves)
    const int lr = lt >> 4;   // step row within chunk (0..31)
    const int lc = lt & 15;   // 16-half column chunk
    u16* ldst = hsH + lr * 320 + 20 * lc;

    if (serialG)
      for (int i = lt; i < 640; i += 512) hcU[i] = 0;  // zero h2 state
    __syncthreads();

    for (int blk = 0; blk < 32; ++blk) {
      // --- pre-phase: dense waves acquire h1 chunk & seed u2 row 0 ---
      if (!serialG && lt == 0) {
        while (__hip_atomic_load(flags + b, __ATOMIC_ACQUIRE,
                                 __HIP_MEMORY_SCOPE_AGENT) < blk + 1)
          __builtin_amdgcn_s_sleep(8);
      }
      __syncthreads();  // B1: flag acquired for all
      if (!serialG) {   // stage h1 chunk [32 steps][256] -> hsH
        const uint4* src =
            (const uint4*)(hb1 + (size_t)(blk * 32 + lr) * Hn + 16 * lc);
        uint4 v0 = src[0], v1 = src[1];  // 32 B = 16 halfs
        ((uint2*)ldst)[0] = make_uint2(v0.x, v0.y);
        ((uint2*)ldst)[1] = make_uint2(v0.z, v0.w);
        ((uint2*)ldst)[2] = make_uint2(v1.x, v1.y);
        ((uint2*)ldst)[3] = make_uint2(v1.z, v1.w);
      }
      __syncthreads();  // B2: staging visible
      if (!serialG) {   // u2 row 0
        float v = colval256(hsH, ks, w);
        if (writer) u2S[jcol] = f2hb(v + b2j);
      }
      __syncthreads();  // B3: row 0 visible

      // --- 32 slices: serial step s || dense u2 row s+1 ---
      for (int g = 0; g < 4; ++g) {
        #pragma unroll
        for (int s8 = 0; s8 < 8; ++s8) {
          const int s = g * 8 + s8;
          if (serialG) {
            const int cu = s & 1, nx = cu ^ 1;
            float uval = hb2f(u2S[s * 272 + jcol]);
            float acc = colval256(hcU + cu * 320, ks, w);
            float h = fast_tanh(acc + uval);
            if (writer) hcU[nx * 320 + woffH] = f2hb(h);
          } else if (s < 31) {
            float v = colval256(hsH + (s + 1) * 320, ks, w);
            if (writer) u2S[(s + 1) * 272 + jcol] = f2hb(v + b2j);
          }
          __syncthreads();
        }
      }
    }
    if (tid < Hn)
      hfinal[(size_t)b * Hn + tid] = hb2f(hcU[(tid >> 4) * 20 + (tid & 15)]);
  }
}

// ---------------------------------------------------------------------------
// Head: out = softmax(h2_T @ Wd + bd). f32, unchanged.
// ---------------------------------------------------------------------------
__global__ __launch_bounds__(128) void head_kernel(
    const float* __restrict__ hfinal, const float* __restrict__ Wd,
    const float* __restrict__ bd, float* __restrict__ out) {
  __shared__ float hrow[Hn];
  __shared__ float red[On];
  const int o = threadIdx.x;
  const int b = blockIdx.x;
  hrow[o] = hfinal[(size_t)b * Hn + o];
  hrow[o + 128] = hfinal[(size_t)b * Hn + 128 + o];
  __syncthreads();
  float acc = bd[o];
  #pragma unroll 8
  for (int k = 0; k < Hn; ++k) acc = fmaf(hrow[k], Wd[(size_t)k * On + o], acc);
  red[o] = acc;
  __syncthreads();
  #pragma unroll
  for (int s = 64; s > 0; s >>= 1) {
    if (o < s) red[o] = fmaxf(red[o], red[o + s]);
    __syncthreads();
  }
  const float mx = red[0];
  __syncthreads();
  const float e = __expf(acc - mx);
  red[o] = e;
  __syncthreads();
  #pragma unroll
  for (int s = 64; s > 0; s >>= 1) {
    if (o < s) red[o] += red[o + s];
    __syncthreads();
  }
  out[(size_t)b * On + o] = e / red[0];
}

// ---------------------------------------------------------------------------
extern "C" void kernel_launch(void* const* d_in, const int* in_sizes, int n_in,
                              void* d_out, int out_size, void* d_ws, size_t ws_size,
                              hipStream_t stream) {
  const float* x   = (const float*)d_in[0];
  const float* Wx1 = (const float*)d_in[1];
  const float* Wh1 = (const float*)d_in[2];
  const float* b1  = (const float*)d_in[3];
  const float* Wx2 = (const float*)d_in[4];
  const float* Wh2 = (const float*)d_in[5];
  const float* b2  = (const float*)d_in[6];
  const float* Wd  = (const float*)d_in[7];
  const float* bd  = (const float*)d_in[8];
  float* out = (float*)d_out;

  u16* h1b16 = (u16*)d_ws;                            // [B,T,256] f16 (64 MB)
  float* hfinal = (float*)(h1b16 + (size_t)Bn * Tn * Hn);  // [B,256] f32
  int* flags = (int*)(hfinal + (size_t)Bn * Hn);      // [B] A->BC

  hipMemsetAsync(flags, 0, Bn * sizeof(int), stream);
  stage1_kernel<<<2 * Bn, 1024, 0, stream>>>(x, Wx1, Wh1, b1, Wx2, b2, Wh2,
                                             h1b16, flags, hfinal);
  head_kernel<<<Bn, 128, 0, stream>>>(hfinal, Wd, bd, out);
}

// Round 10
// 1087.481 us; speedup vs baseline: 1.0718x; 1.0599x over previous
//
#include <hip/hip_runtime.h>
#include <cstdint>

constexpr int Bn = 128, Tn = 1024, Dn = 64, Hn = 256, On = 128;

typedef __fp16 h2 __attribute__((ext_vector_type(2)));
typedef __fp16 half8_t __attribute__((ext_vector_type(8)));
typedef float f32x4 __attribute__((ext_vector_type(4)));
typedef unsigned short u16;

__device__ __forceinline__ float fast_tanh(float x) {
  float e = __expf(2.0f * x);
  return 1.0f - 2.0f / (e + 1.0f);
}
__device__ __forceinline__ float fdot2(h2 a, h2 b, float c) {
#if __has_builtin(__builtin_amdgcn_fdot2)
  return __builtin_amdgcn_fdot2(a, b, c, false);
#else
  return fmaf((float)a.y, (float)b.y, fmaf((float)a.x, (float)b.x, c));
#endif
}
__device__ __forceinline__ h2 pk2(float a, float b) {
  h2 r; r.x = (__fp16)a; r.y = (__fp16)b; return r;
}
__device__ __forceinline__ h2 bits2h(unsigned u) { return __builtin_bit_cast(h2, u); }
__device__ __forceinline__ unsigned h2bits(h2 v) { return __builtin_bit_cast(unsigned, v); }
__device__ __forceinline__ u16 f2hb(float f) {
  __fp16 h = (__fp16)f; return __builtin_bit_cast(u16, h);
}
__device__ __forceinline__ float hb2f(u16 b) {
  return (float)__builtin_bit_cast(__fp16, b);
}

template <int CTRL>
__device__ __forceinline__ float dpp_add(float v) {
  int s = __builtin_amdgcn_update_dpp(0, __float_as_int(v), CTRL, 0xF, 0xF, true);
  return v + __int_as_float(s);
}
__device__ __forceinline__ float row16_sum(float v) {
  v = dpp_add<0xB1>(v);   // quad_perm xor1
  v = dpp_add<0x4E>(v);   // quad_perm xor2
  v = dpp_add<0x141>(v);  // xor4
  v = dpp_add<0x140>(v);  // xor8
  return v;
}
__device__ __forceinline__ float sel8(int ks, float s0, float s1, float s2,
                                      float s3, float s4, float s5, float s6,
                                      float s7) {
  float u0 = (ks & 1) ? s1 : s0;
  float u1 = (ks & 1) ? s3 : s2;
  float u2 = (ks & 1) ? s5 : s4;
  float u3 = (ks & 1) ? s7 : s6;
  float v0 = (ks & 2) ? u1 : u0;
  float v1 = (ks & 2) ? u3 : u2;
  return (ks & 4) ? v1 : v0;
}

// ---------------------------------------------------------------------------
// Dense matvec helpers (v_dot path, throughput waves). Weights are packed
// 4 k-pairs per half8_t slot: logical w[p][c] -> wfr[p] comp c (c<4),
// wfr[p+8] comp c-4. AGPR residency + accvgpr_read cost is fine here.
// ---------------------------------------------------------------------------
__device__ __forceinline__ float dense_row256(const u16* rowbase, int ks,
                                              const half8_t (&wfr)[16]) {
  const uint2* hq = (const uint2*)(rowbase + 20 * ks);
  uint2 q0 = hq[0], q1 = hq[1], q2 = hq[2], q3 = hq[3];
  float a0 = 0.f, a1 = 0.f, a2 = 0.f, a3 = 0.f,
        a4 = 0.f, a5 = 0.f, a6 = 0.f, a7 = 0.f;
  const unsigned d[8] = {q0.x, q0.y, q1.x, q1.y, q2.x, q2.y, q3.x, q3.y};
  #pragma unroll
  for (int p = 0; p < 8; ++p) {
    h2 hp = bits2h(d[p]);
    uint4 lo = __builtin_bit_cast(uint4, wfr[p]);
    uint4 hi = __builtin_bit_cast(uint4, wfr[p + 8]);
    a0 = fdot2(hp, bits2h(lo.x), a0);
    a1 = fdot2(hp, bits2h(lo.y), a1);
    a2 = fdot2(hp, bits2h(lo.z), a2);
    a3 = fdot2(hp, bits2h(lo.w), a3);
    a4 = fdot2(hp, bits2h(hi.x), a4);
    a5 = fdot2(hp, bits2h(hi.y), a5);
    a6 = fdot2(hp, bits2h(hi.z), a6);
    a7 = fdot2(hp, bits2h(hi.w), a7);
  }
  float s0 = row16_sum(a0), s1 = row16_sum(a1);
  float s2 = row16_sum(a2), s3 = row16_sum(a3);
  float s4 = row16_sum(a4), s5 = row16_sum(a5);
  float s6 = row16_sum(a6), s7 = row16_sum(a7);
  return sel8(ks, s0, s1, s2, s3, s4, s5, s6, s7);
}
// K=64 variant for u1 = x@Wx1 (x row in plain [64]-half layout).
__device__ __forceinline__ float dense_row64(const u16* xrow, int ks,
                                             const half8_t (&wfr)[16]) {
  uint2 xq = *(const uint2*)(xrow + 4 * ks);
  h2 xp0 = bits2h(xq.x), xp1 = bits2h(xq.y);
  uint4 lo0 = __builtin_bit_cast(uint4, wfr[0]);
  uint4 lo1 = __builtin_bit_cast(uint4, wfr[1]);
  uint4 hi0 = __builtin_bit_cast(uint4, wfr[8]);
  uint4 hi1 = __builtin_bit_cast(uint4, wfr[9]);
  float a0 = 0.f, a1 = 0.f, a2 = 0.f, a3 = 0.f,
        a4 = 0.f, a5 = 0.f, a6 = 0.f, a7 = 0.f;
  a0 = fdot2(xp0, bits2h(lo0.x), a0); a0 = fdot2(xp1, bits2h(lo1.x), a0);
  a1 = fdot2(xp0, bits2h(lo0.y), a1); a1 = fdot2(xp1, bits2h(lo1.y), a1);
  a2 = fdot2(xp0, bits2h(lo0.z), a2); a2 = fdot2(xp1, bits2h(lo1.z), a2);
  a3 = fdot2(xp0, bits2h(lo0.w), a3); a3 = fdot2(xp1, bits2h(lo1.w), a3);
  a4 = fdot2(xp0, bits2h(hi0.x), a4); a4 = fdot2(xp1, bits2h(hi1.x), a4);
  a5 = fdot2(xp0, bits2h(hi0.y), a5); a5 = fdot2(xp1, bits2h(hi1.y), a5);
  a6 = fdot2(xp0, bits2h(hi0.z), a6); a6 = fdot2(xp1, bits2h(hi1.z), a6);
  a7 = fdot2(xp0, bits2h(hi0.w), a7); a7 = fdot2(xp1, bits2h(hi1.w), a7);
  float s0 = row16_sum(a0), s1 = row16_sum(a1);
  float s2 = row16_sum(a2), s3 = row16_sum(a3);
  float s4 = row16_sum(a4), s5 = row16_sum(a5);
  float s6 = row16_sum(a6), s7 = row16_sum(a7);
  return sel8(ks, s0, s1, s2, s3, s4, s5, s6, s7);
}

// ---------------------------------------------------------------------------
// MFMA serial matvec: h(256) @ W(256x256) -> 32 cols per wave (2 colgroups).
// B-frags (weights) live in AGPRs -- MFMA reads them natively (isa §10),
// which is the whole point: the 1024-thr config's 64/64 arch/AGPR split
// (rounds 7-9: arch capped at 64, immovable) stops hurting.
// A-operand: h-slice broadcast to all 16 rows (lane's k-oct = l>>4), so
// every D row equals h@W -- only the verified col=lane&15 C/D map matters,
// and any k-permutation inside the frag cancels (A,B use the same map).
// ---------------------------------------------------------------------------
__device__ __forceinline__ void mfma_step(const u16* hcB, int oh, int ol,
                                          const half8_t (&wfr)[16],
                                          float& v0, float& v1) {
  f32x4 ac0 = {0.f, 0.f, 0.f, 0.f}, ac1 = {0.f, 0.f, 0.f, 0.f};
  #pragma unroll
  for (int kt = 0; kt < 8; ++kt) {
    // h[32kt + 8*(l>>4) .. +7] in the 20-stride slice layout:
    // halfs offset = 40*kt + 20*oh + 8*ol  (oh=(l>>5), ol=(l>>4)&1)
    const u16* ap = hcB + 40 * kt + 20 * oh + 8 * ol;
    uint2 r0 = *(const uint2*)ap;
    uint2 r1 = *(const uint2*)(ap + 4);
    half8_t af = __builtin_bit_cast(half8_t, make_uint4(r0.x, r0.y, r1.x, r1.y));
    ac0 = __builtin_amdgcn_mfma_f32_16x16x32_f16(af, wfr[kt], ac0, 0, 0, 0);
    ac1 = __builtin_amdgcn_mfma_f32_16x16x32_f16(af, wfr[8 + kt], ac1, 0, 0, 0);
  }
  v0 = ac0[0];
  v1 = ac1[0];
}

// LDS h layout (f16): 16 slices x (16 data + 4 pad) halfs; slice stride 40 B.
// ---------------------------------------------------------------------------
// Fused pipeline, 256 WGs x 1024 threads == 1 block/CU.
//   role A  (blocks 0..127): waves 0-7 serial scan1 via MFMA (Wh1 frags in
//       AGPR); waves 8-15 dense: stage x chunk + u1 = x@Wx1+b1 rows (row s+1
//       during slice s, row 0 in pre-phase) -- round-7's proven schedule.
//   role BC (blocks 128..255): waves 0-7 serial scan2 via MFMA (Wh2 frags);
//       waves 8-15 dense u2 = h1@Wx2+b2 (round-7 code, wfr-packed weights).
//   Serial and dense weight arrays are UNIONED into one half8_t wfr[16]
//   (64 regs) so the per-kernel live set fits the 64/64 split.
// ---------------------------------------------------------------------------
__global__ __launch_bounds__(1024)
__attribute__((amdgpu_waves_per_eu(4, 4))) void stage1_kernel(
    const float* __restrict__ x,    // [B,T,64] f32
    const float* __restrict__ Wx1,  // [64,256] f32
    const float* __restrict__ Wh1,  // [256,256] f32
    const float* __restrict__ b1,   // [256]
    const float* __restrict__ Wx2,  // [256,256] f32
    const float* __restrict__ b2,   // [256]
    const float* __restrict__ Wh2,  // [256,256] f32
    u16* __restrict__ h1b16,        // [B,T,256] f16 h1 (A -> BC channel)
    int* __restrict__ flags,        // [B]  A -> BC progress (32-step chunks)
    float* __restrict__ hfinal) {   // [B,256] f32 (role BC output)
  __shared__ alignas(16) u16 smemU[19584];  // 38.25 KB
  const int tid = threadIdx.x;
  const unsigned bid = blockIdx.x;
  const bool roleA = (bid < (unsigned)Bn);
  const bool serialG = (tid < 512);

  // ---- common index math ----
  // serial lanes:
  const int w_ = tid >> 6;          // wave 0..7
  const int l = tid & 63;
  const int oh = (l >> 5) & 1;      // k-oct high bit
  const int ol = (l >> 4) & 1;      // k-oct low bit
  const int jc = 32 * w_ + (l & 15);  // colgroup-0 column
  const int woff0 = 40 * w_ + (l & 15);
  // dense lanes:
  const int lt = tid & 511;
  const int ks = lt & 15;
  const int cg = lt >> 4;
  const int col0 = 8 * cg;
  const int jcol = col0 + (ks & 7);
  const bool writerD = (ks < 8);

  half8_t wfr[16];  // union: serial B-frags OR dense packed k-pairs

  if (serialG) {
    // Serial weights: B-frag (g,kt): lane l holds W[32kt+8(l>>4)+e][32w+16g+(l&15)]
    const float* Wser = roleA ? Wh1 : Wh2;
    const int ko = 8 * (l >> 4);
    #pragma unroll
    for (int g = 0; g < 2; ++g)
      #pragma unroll
      for (int kt = 0; kt < 8; ++kt) {
        const float* wp = Wser + (size_t)(32 * kt + ko) * Hn + jc + 16 * g;
        half8_t f;
        #pragma unroll
        for (int e = 0; e < 8; ++e) f[e] = (__fp16)wp[(size_t)e * Hn];
        wfr[g * 8 + kt] = f;
      }
  } else if (roleA) {
    // Dense-A weights: Wx1 k-pairs (4ks+2p,+1) x 8 cols, packed (p=0..1)
    #pragma unroll
    for (int p = 0; p < 2; ++p) {
      const float* r0 = Wx1 + (size_t)(4 * ks + 2 * p) * Hn + col0;
      float4 a0 = *(const float4*)r0, a1 = *(const float4*)(r0 + 4);
      float4 c0 = *(const float4*)(r0 + Hn), c1 = *(const float4*)(r0 + Hn + 4);
      wfr[p] = __builtin_bit_cast(half8_t,
          make_uint4(h2bits(pk2(a0.x, c0.x)), h2bits(pk2(a0.y, c0.y)),
                     h2bits(pk2(a0.z, c0.z)), h2bits(pk2(a0.w, c0.w))));
      wfr[p + 8] = __builtin_bit_cast(half8_t,
          make_uint4(h2bits(pk2(a1.x, c1.x)), h2bits(pk2(a1.y, c1.y)),
                     h2bits(pk2(a1.z, c1.z)), h2bits(pk2(a1.w, c1.w))));
    }
  } else {
    // Dense-BC weights: Wx2 k-pairs (16ks+2p,+1) x 8 cols, packed (p=0..7)
    #pragma unroll
    for (int p = 0; p < 8; ++p) {
      const float* r0 = Wx2 + (size_t)(16 * ks + 2 * p) * Hn + col0;
      float4 a0 = *(const float4*)r0, a1 = *(const float4*)(r0 + 4);
      float4 c0 = *(const float4*)(r0 + Hn), c1 = *(const float4*)(r0 + Hn + 4);
      wfr[p] = __builtin_bit_cast(half8_t,
          make_uint4(h2bits(pk2(a0.x, c0.x)), h2bits(pk2(a0.y, c0.y)),
                     h2bits(pk2(a0.z, c0.z)), h2bits(pk2(a0.w, c0.w))));
      wfr[p + 8] = __builtin_bit_cast(half8_t,
          make_uint4(h2bits(pk2(a1.x, c1.x)), h2bits(pk2(a1.y, c1.y)),
                     h2bits(pk2(a1.z, c1.z)), h2bits(pk2(a1.w, c1.w))));
    }
  }

  if (roleA) {
    // ==================== ROLE A ====================
    const int b = bid;
    const float* xb = x + (size_t)b * Tn * Dn;
    u16* hb = h1b16 + (size_t)b * Tn * Hn;
    u16* hcH = smemU;            // 640 halfs: 2 x 320 h-state
    u16* xs = smemU + 640;       // 2048 halfs: x chunk [32][64] f16
    u16* u1S = smemU + 2688;     // 8704 halfs: u1 [32][272]
    const float bj = b1[jcol];   // dense bias

    if (serialG)
      for (int i = tid; i < 640; i += 512) hcH[i] = 0;
    __syncthreads();

    for (int ch = 0; ch < 32; ++ch) {
      // pre1: dense stages x chunk ch -> xs (f16)
      if (!serialG) {
        const float* xsrc = xb + (size_t)ch * 2048 + (lt >> 4) * 64 + (lt & 15) * 4;
        float4 f = *(const float4*)xsrc;
        *(uint2*)(xs + (lt >> 4) * 64 + (lt & 15) * 4) =
            make_uint2(h2bits(pk2(f.x, f.y)), h2bits(pk2(f.z, f.w)));
      }
      __syncthreads();
      // pre2: dense computes u1 row 0
      if (!serialG) {
        float v = dense_row64(xs, ks, wfr);
        if (writerD) u1S[jcol] = f2hb(v + bj);
      }
      __syncthreads();
      // 32 slices: serial step s || dense u1 row s+1
      for (int g4 = 0; g4 < 4; ++g4) {
        u16 hreg0[8], hreg1[8];
        #pragma unroll
        for (int s8 = 0; s8 < 8; ++s8) {
          const int s = g4 * 8 + s8;
          if (serialG) {
            const int cu = s & 1, nx = cu ^ 1;
            float uv0 = hb2f(u1S[s * 272 + jc]);
            float uv1 = hb2f(u1S[s * 272 + jc + 16]);
            float v0, v1;
            mfma_step(hcH + cu * 320, oh, ol, wfr, v0, v1);
            u16 h0 = f2hb(fast_tanh(v0 + uv0));
            u16 h1 = f2hb(fast_tanh(v1 + uv1));
            if (l < 16) {
              hcH[nx * 320 + woff0] = h0;
              hcH[nx * 320 + woff0 + 20] = h1;
            }
            hreg0[s8] = h0;
            hreg1[s8] = h1;
            if (s8 == 7 && l < 16) {
              u16* d0 = hb + (size_t)(32 * ch + s - 7) * Hn + jc;
              #pragma unroll
              for (int i = 0; i < 8; ++i) {
                d0[i * Hn] = hreg0[i];
                d0[i * Hn + 16] = hreg1[i];
              }
            }
          } else if (s < 31) {
            float v = dense_row64(xs + (s + 1) * 64, ks, wfr);
            if (writerD) u1S[(s + 1) * 272 + jcol] = f2hb(v + bj);
          }
          __syncthreads();  // drains vmem (incl. h1 stores at s8==7)
        }
      }
      if (tid == 0)
        __hip_atomic_store(flags + b, ch + 1, __ATOMIC_RELEASE,
                           __HIP_MEMORY_SCOPE_AGENT);
    }
  } else {
    // ==================== ROLE BC ====================
    const int b = bid - Bn;
    const u16* hb1 = h1b16 + (size_t)b * Tn * Hn;
    u16* hsH = smemU;            // [32][320] halfs (h1 staging)
    u16* u2S = smemU + 10240;    // [32][272] halfs (u2)
    u16* hcU = smemU + 18944;    // 2 x 320 halfs (h2 state)
    const float bj = b2[jcol];   // dense bias
    u16* ldst = hsH + (lt >> 4) * 320 + 20 * (lt & 15);

    if (serialG)
      for (int i = tid; i < 640; i += 512) hcU[i] = 0;
    __syncthreads();

    for (int ch = 0; ch < 32; ++ch) {
      if (!serialG && lt == 0) {
        while (__hip_atomic_load(flags + b, __ATOMIC_ACQUIRE,
                                 __HIP_MEMORY_SCOPE_AGENT) < ch + 1)
          __builtin_amdgcn_s_sleep(8);
      }
      __syncthreads();  // flag acquired
      if (!serialG) {   // stage h1 chunk [32][256] -> hsH (slice layout)
        const uint4* src =
            (const uint4*)(hb1 + (size_t)(ch * 32 + (lt >> 4)) * Hn + 16 * (lt & 15));
        uint4 v0 = src[0], v1 = src[1];
        ((uint2*)ldst)[0] = make_uint2(v0.x, v0.y);
        ((uint2*)ldst)[1] = make_uint2(v0.z, v0.w);
        ((uint2*)ldst)[2] = make_uint2(v1.x, v1.y);
        ((uint2*)ldst)[3] = make_uint2(v1.z, v1.w);
      }
      __syncthreads();  // staged
      if (!serialG) {   // u2 row 0
        float v = dense_row256(hsH, ks, wfr);
        if (writerD) u2S[jcol] = f2hb(v + bj);
      }
      __syncthreads();  // row 0 visible

      for (int g4 = 0; g4 < 4; ++g4) {
        #pragma unroll
        for (int s8 = 0; s8 < 8; ++s8) {
          const int s = g4 * 8 + s8;
          if (serialG) {
            const int cu = s & 1, nx = cu ^ 1;
            float uv0 = hb2f(u2S[s * 272 + jc]);
            float uv1 = hb2f(u2S[s * 272 + jc + 16]);
            float v0, v1;
            mfma_step(hcU + cu * 320, oh, ol, wfr, v0, v1);
            if (l < 16) {
              hcU[nx * 320 + woff0] = f2hb(fast_tanh(v0 + uv0));
              hcU[nx * 320 + woff0 + 20] = f2hb(fast_tanh(v1 + uv1));
            }
          } else if (s < 31) {
            float v = dense_row256(hsH + (s + 1) * 320, ks, wfr);
            if (writerD) u2S[(s + 1) * 272 + jcol] = f2hb(v + bj);
          }
          __syncthreads();
        }
      }
    }
    if (tid < Hn)
      hfinal[(size_t)b * Hn + tid] = hb2f(hcU[(tid >> 4) * 20 + (tid & 15)]);
  }
}

// ---------------------------------------------------------------------------
// Head: out = softmax(h2_T @ Wd + bd). f32, unchanged.
// ---------------------------------------------------------------------------
__global__ __launch_bounds__(128) void head_kernel(
    const float* __restrict__ hfinal, const float* __restrict__ Wd,
    const float* __restrict__ bd, float* __restrict__ out) {
  __shared__ float hrow[Hn];
  __shared__ float red[On];
  const int o = threadIdx.x;
  const int b = blockIdx.x;
  hrow[o] = hfinal[(size_t)b * Hn + o];
  hrow[o + 128] = hfinal[(size_t)b * Hn + 128 + o];
  __syncthreads();
  float acc = bd[o];
  #pragma unroll 8
  for (int k = 0; k < Hn; ++k) acc = fmaf(hrow[k], Wd[(size_t)k * On + o], acc);
  red[o] = acc;
  __syncthreads();
  #pragma unroll
  for (int s = 64; s > 0; s >>= 1) {
    if (o < s) red[o] = fmaxf(red[o], red[o + s]);
    __syncthreads();
  }
  const float mx = red[0];
  __syncthreads();
  const float e = __expf(acc - mx);
  red[o] = e;
  __syncthreads();
  #pragma unroll
  for (int s = 64; s > 0; s >>= 1) {
    if (o < s) red[o] += red[o + s];
    __syncthreads();
  }
  out[(size_t)b * On + o] = e / red[0];
}

// ---------------------------------------------------------------------------
extern "C" void kernel_launch(void* const* d_in, const int* in_sizes, int n_in,
                              void* d_out, int out_size, void* d_ws, size_t ws_size,
                              hipStream_t stream) {
  const float* x   = (const float*)d_in[0];
  const float* Wx1 = (const float*)d_in[1];
  const float* Wh1 = (const float*)d_in[2];
  const float* b1  = (const float*)d_in[3];
  const float* Wx2 = (const float*)d_in[4];
  const float* Wh2 = (const float*)d_in[5];
  const float* b2  = (const float*)d_in[6];
  const float* Wd  = (const float*)d_in[7];
  const float* bd  = (const float*)d_in[8];
  float* out = (float*)d_out;

  u16* h1b16 = (u16*)d_ws;                            // [B,T,256] f16 (64 MB)
  float* hfinal = (float*)(h1b16 + (size_t)Bn * Tn * Hn);  // [B,256] f32
  int* flags = (int*)(hfinal + (size_t)Bn * Hn);      // [B] A->BC

  hipMemsetAsync(flags, 0, Bn * sizeof(int), stream);
  stage1_kernel<<<2 * Bn, 1024, 0, stream>>>(x, Wx1, Wh1, b1, Wx2, b2, Wh2,
                                             h1b16, flags, hfinal);
  head_kernel<<<Bn, 128, 0, stream>>>(hfinal, Wd, bd, out);
}

// Round 11
// 1081.520 us; speedup vs baseline: 1.0777x; 1.0055x over previous
//
#include <hip/hip_runtime.h>
#include <cstdint>

constexpr int Bn = 128, Tn = 1024, Dn = 64, Hn = 256, On = 128;

typedef __fp16 h2 __attribute__((ext_vector_type(2)));
typedef __fp16 half8_t __attribute__((ext_vector_type(8)));
typedef float f32x4 __attribute__((ext_vector_type(4)));
typedef unsigned short u16;

__device__ __forceinline__ float fast_tanh(float x) {
  float e = __expf(2.0f * x);
  return 1.0f - 2.0f / (e + 1.0f);
}
__device__ __forceinline__ float fdot2(h2 a, h2 b, float c) {
#if __has_builtin(__builtin_amdgcn_fdot2)
  return __builtin_amdgcn_fdot2(a, b, c, false);
#else
  return fmaf((float)a.y, (float)b.y, fmaf((float)a.x, (float)b.x, c));
#endif
}
__device__ __forceinline__ h2 pk2(float a, float b) {
  h2 r; r.x = (__fp16)a; r.y = (__fp16)b; return r;
}
__device__ __forceinline__ h2 bits2h(unsigned u) { return __builtin_bit_cast(h2, u); }
__device__ __forceinline__ unsigned h2bits(h2 v) { return __builtin_bit_cast(unsigned, v); }
__device__ __forceinline__ u16 f2hb(float f) {
  __fp16 h = (__fp16)f; return __builtin_bit_cast(u16, h);
}
__device__ __forceinline__ float hb2f(u16 b) {
  return (float)__builtin_bit_cast(__fp16, b);
}

template <int CTRL>
__device__ __forceinline__ float dpp_add(float v) {
  int s = __builtin_amdgcn_update_dpp(0, __float_as_int(v), CTRL, 0xF, 0xF, true);
  return v + __int_as_float(s);
}
__device__ __forceinline__ float row16_sum(float v) {
  v = dpp_add<0xB1>(v);   // quad_perm xor1
  v = dpp_add<0x4E>(v);   // quad_perm xor2
  v = dpp_add<0x141>(v);  // xor4
  v = dpp_add<0x140>(v);  // xor8
  return v;
}
__device__ __forceinline__ float sel8(int ks, float s0, float s1, float s2,
                                      float s3, float s4, float s5, float s6,
                                      float s7) {
  float u0 = (ks & 1) ? s1 : s0;
  float u1 = (ks & 1) ? s3 : s2;
  float u2 = (ks & 1) ? s5 : s4;
  float u3 = (ks & 1) ? s7 : s6;
  float v0 = (ks & 2) ? u1 : u0;
  float v1 = (ks & 2) ? u3 : u2;
  return (ks & 4) ? v1 : v0;
}

// ---------------------------------------------------------------------------
// Dense matvec helpers (v_dot path, throughput waves). Weights are packed
// 4 k-pairs per half8_t slot: logical w[p][c] -> wfr[p] comp c (c<4),
// wfr[p+8] comp c-4. AGPR residency + accvgpr_read cost is fine here.
// ---------------------------------------------------------------------------
__device__ __forceinline__ float dense_row256(const u16* rowbase, int ks,
                                              const half8_t (&wfr)[16]) {
  const uint2* hq = (const uint2*)(rowbase + 20 * ks);
  uint2 q0 = hq[0], q1 = hq[1], q2 = hq[2], q3 = hq[3];
  float a0 = 0.f, a1 = 0.f, a2 = 0.f, a3 = 0.f,
        a4 = 0.f, a5 = 0.f, a6 = 0.f, a7 = 0.f;
  const unsigned d[8] = {q0.x, q0.y, q1.x, q1.y, q2.x, q2.y, q3.x, q3.y};
  #pragma unroll
  for (int p = 0; p < 8; ++p) {
    h2 hp = bits2h(d[p]);
    uint4 lo = __builtin_bit_cast(uint4, wfr[p]);
    uint4 hi = __builtin_bit_cast(uint4, wfr[p + 8]);
    a0 = fdot2(hp, bits2h(lo.x), a0);
    a1 = fdot2(hp, bits2h(lo.y), a1);
    a2 = fdot2(hp, bits2h(lo.z), a2);
    a3 = fdot2(hp, bits2h(lo.w), a3);
    a4 = fdot2(hp, bits2h(hi.x), a4);
    a5 = fdot2(hp, bits2h(hi.y), a5);
    a6 = fdot2(hp, bits2h(hi.z), a6);
    a7 = fdot2(hp, bits2h(hi.w), a7);
  }
  float s0 = row16_sum(a0), s1 = row16_sum(a1);
  float s2 = row16_sum(a2), s3 = row16_sum(a3);
  float s4 = row16_sum(a4), s5 = row16_sum(a5);
  float s6 = row16_sum(a6), s7 = row16_sum(a7);
  return sel8(ks, s0, s1, s2, s3, s4, s5, s6, s7);
}
// K=64 variant for u1 = x@Wx1 (x row in plain [64]-half layout).
__device__ __forceinline__ float dense_row64(const u16* xrow, int ks,
                                             const half8_t (&wfr)[16]) {
  uint2 xq = *(const uint2*)(xrow + 4 * ks);
  h2 xp0 = bits2h(xq.x), xp1 = bits2h(xq.y);
  uint4 lo0 = __builtin_bit_cast(uint4, wfr[0]);
  uint4 lo1 = __builtin_bit_cast(uint4, wfr[1]);
  uint4 hi0 = __builtin_bit_cast(uint4, wfr[8]);
  uint4 hi1 = __builtin_bit_cast(uint4, wfr[9]);
  float a0 = 0.f, a1 = 0.f, a2 = 0.f, a3 = 0.f,
        a4 = 0.f, a5 = 0.f, a6 = 0.f, a7 = 0.f;
  a0 = fdot2(xp0, bits2h(lo0.x), a0); a0 = fdot2(xp1, bits2h(lo1.x), a0);
  a1 = fdot2(xp0, bits2h(lo0.y), a1); a1 = fdot2(xp1, bits2h(lo1.y), a1);
  a2 = fdot2(xp0, bits2h(lo0.z), a2); a2 = fdot2(xp1, bits2h(lo1.z), a2);
  a3 = fdot2(xp0, bits2h(lo0.w), a3); a3 = fdot2(xp1, bits2h(lo1.w), a3);
  a4 = fdot2(xp0, bits2h(hi0.x), a4); a4 = fdot2(xp1, bits2h(hi1.x), a4);
  a5 = fdot2(xp0, bits2h(hi0.y), a5); a5 = fdot2(xp1, bits2h(hi1.y), a5);
  a6 = fdot2(xp0, bits2h(hi0.z), a6); a6 = fdot2(xp1, bits2h(hi1.z), a6);
  a7 = fdot2(xp0, bits2h(hi0.w), a7); a7 = fdot2(xp1, bits2h(hi1.w), a7);
  float s0 = row16_sum(a0), s1 = row16_sum(a1);
  float s2 = row16_sum(a2), s3 = row16_sum(a3);
  float s4 = row16_sum(a4), s5 = row16_sum(a5);
  float s6 = row16_sum(a6), s7 = row16_sum(a7);
  return sel8(ks, s0, s1, s2, s3, s4, s5, s6, s7);
}

// ---------------------------------------------------------------------------
// MFMA serial matvec. Round-11 change: PREFETCH all 16 A-fragment halves
// (ds_read_b64 x16) into explicit arrays BEFORE the MFMA chain. Round 10's
// interleaved form serialized under the 64-arch-VGPR ceiling: read -> wait
// ~120cy -> mfma -> read ... = ~1000cy of raw LDS latency per step. With
// all reads outstanding together, one wait covers them (lgkmcnt counts
// down as the chain consumes). Live set: 32 frag regs + 8 acc + misc < 64.
// B-frags (weights) stay in AGPRs -- MFMA reads them natively (isa §10).
// ---------------------------------------------------------------------------
__device__ __forceinline__ void mfma_step(const u16* hcB, int oh, int ol,
                                          const half8_t (&wfr)[16],
                                          float& v0, float& v1) {
  uint2 ra[8], rb[8];
  #pragma unroll
  for (int kt = 0; kt < 8; ++kt) {
    const u16* ap = hcB + 40 * kt + 20 * oh + 8 * ol;
    ra[kt] = *(const uint2*)ap;
    rb[kt] = *(const uint2*)(ap + 4);
  }
  f32x4 ac0 = {0.f, 0.f, 0.f, 0.f}, ac1 = {0.f, 0.f, 0.f, 0.f};
  #pragma unroll
  for (int kt = 0; kt < 8; ++kt) {
    half8_t af = __builtin_bit_cast(
        half8_t, make_uint4(ra[kt].x, ra[kt].y, rb[kt].x, rb[kt].y));
    ac0 = __builtin_amdgcn_mfma_f32_16x16x32_f16(af, wfr[kt], ac0, 0, 0, 0);
    ac1 = __builtin_amdgcn_mfma_f32_16x16x32_f16(af, wfr[8 + kt], ac1, 0, 0, 0);
  }
  v0 = ac0[0];
  v1 = ac1[0];
}

// LDS h layout (f16): 16 slices x (16 data + 4 pad) halfs; slice stride 40 B.
// ---------------------------------------------------------------------------
// Fused pipeline, 256 WGs x 1024 threads == 1 block/CU.
//   role A  (blocks 0..127): waves 0-7 serial scan1 via MFMA (Wh1 frags in
//       AGPR); waves 8-15 dense: stage x chunk + u1 = x@Wx1+b1 rows (row s+1
//       during slice s, row 0 in pre-phase).
//   role BC (blocks 128..255): waves 0-7 serial scan2 via MFMA (Wh2 frags);
//       waves 8-15 dense u2 = h1@Wx2+b2.
//   Serial and dense weight arrays are UNIONED into one half8_t wfr[16]
//   (64 regs) matching the 1024-thr config's immutable 64/64 arch/AGPR
//   split (rounds 7-9: arch capped at 64 regardless of asm/attributes).
// ---------------------------------------------------------------------------
__global__ __launch_bounds__(1024)
__attribute__((amdgpu_waves_per_eu(4, 4))) void stage1_kernel(
    const float* __restrict__ x,    // [B,T,64] f32
    const float* __restrict__ Wx1,  // [64,256] f32
    const float* __restrict__ Wh1,  // [256,256] f32
    const float* __restrict__ b1,   // [256]
    const float* __restrict__ Wx2,  // [256,256] f32
    const float* __restrict__ b2,   // [256]
    const float* __restrict__ Wh2,  // [256,256] f32
    u16* __restrict__ h1b16,        // [B,T,256] f16 h1 (A -> BC channel)
    int* __restrict__ flags,        // [B]  A -> BC progress (32-step chunks)
    float* __restrict__ hfinal) {   // [B,256] f32 (role BC output)
  __shared__ alignas(16) u16 smemU[19584];  // 38.25 KB
  const int tid = threadIdx.x;
  const unsigned bid = blockIdx.x;
  const bool roleA = (bid < (unsigned)Bn);
  const bool serialG = (tid < 512);

  // ---- common index math ----
  // serial lanes:
  const int w_ = tid >> 6;          // wave 0..7
  const int l = tid & 63;
  const int oh = (l >> 5) & 1;      // k-oct high bit
  const int ol = (l >> 4) & 1;      // k-oct low bit
  const int jc = 32 * w_ + (l & 15);  // colgroup-0 column
  const int woff0 = 40 * w_ + (l & 15);
  // dense lanes:
  const int lt = tid & 511;
  const int ks = lt & 15;
  const int cg = lt >> 4;
  const int col0 = 8 * cg;
  const int jcol = col0 + (ks & 7);
  const bool writerD = (ks < 8);

  half8_t wfr[16];  // union: serial B-frags OR dense packed k-pairs

  if (serialG) {
    // Serial weights: B-frag (g,kt): lane l holds W[32kt+8(l>>4)+e][32w+16g+(l&15)]
    const float* Wser = roleA ? Wh1 : Wh2;
    const int ko = 8 * (l >> 4);
    #pragma unroll
    for (int g = 0; g < 2; ++g)
      #pragma unroll
      for (int kt = 0; kt < 8; ++kt) {
        const float* wp = Wser + (size_t)(32 * kt + ko) * Hn + jc + 16 * g;
        half8_t f;
        #pragma unroll
        for (int e = 0; e < 8; ++e) f[e] = (__fp16)wp[(size_t)e * Hn];
        wfr[g * 8 + kt] = f;
      }
  } else if (roleA) {
    // Dense-A weights: Wx1 k-pairs (4ks+2p,+1) x 8 cols, packed (p=0..1)
    #pragma unroll
    for (int p = 0; p < 2; ++p) {
      const float* r0 = Wx1 + (size_t)(4 * ks + 2 * p) * Hn + col0;
      float4 a0 = *(const float4*)r0, a1 = *(const float4*)(r0 + 4);
      float4 c0 = *(const float4*)(r0 + Hn), c1 = *(const float4*)(r0 + Hn + 4);
      wfr[p] = __builtin_bit_cast(half8_t,
          make_uint4(h2bits(pk2(a0.x, c0.x)), h2bits(pk2(a0.y, c0.y)),
                     h2bits(pk2(a0.z, c0.z)), h2bits(pk2(a0.w, c0.w))));
      wfr[p + 8] = __builtin_bit_cast(half8_t,
          make_uint4(h2bits(pk2(a1.x, c1.x)), h2bits(pk2(a1.y, c1.y)),
                     h2bits(pk2(a1.z, c1.z)), h2bits(pk2(a1.w, c1.w))));
    }
  } else {
    // Dense-BC weights: Wx2 k-pairs (16ks+2p,+1) x 8 cols, packed (p=0..7)
    #pragma unroll
    for (int p = 0; p < 8; ++p) {
      const float* r0 = Wx2 + (size_t)(16 * ks + 2 * p) * Hn + col0;
      float4 a0 = *(const float4*)r0, a1 = *(const float4*)(r0 + 4);
      float4 c0 = *(const float4*)(r0 + Hn), c1 = *(const float4*)(r0 + Hn + 4);
      wfr[p] = __builtin_bit_cast(half8_t,
          make_uint4(h2bits(pk2(a0.x, c0.x)), h2bits(pk2(a0.y, c0.y)),
                     h2bits(pk2(a0.z, c0.z)), h2bits(pk2(a0.w, c0.w))));
      wfr[p + 8] = __builtin_bit_cast(half8_t,
          make_uint4(h2bits(pk2(a1.x, c1.x)), h2bits(pk2(a1.y, c1.y)),
                     h2bits(pk2(a1.z, c1.z)), h2bits(pk2(a1.w, c1.w))));
    }
  }

  if (roleA) {
    // ==================== ROLE A ====================
    const int b = bid;
    const float* xb = x + (size_t)b * Tn * Dn;
    u16* hb = h1b16 + (size_t)b * Tn * Hn;
    u16* hcH = smemU;            // 640 halfs: 2 x 320 h-state
    u16* xs = smemU + 640;       // 2048 halfs: x chunk [32][64] f16
    u16* u1S = smemU + 2688;     // 8704 halfs: u1 [32][272]
    const float bj = b1[jcol];   // dense bias

    if (serialG)
      for (int i = tid; i < 640; i += 512) hcH[i] = 0;
    __syncthreads();

    for (int ch = 0; ch < 32; ++ch) {
      // pre1: dense stages x chunk ch -> xs (f16)
      if (!serialG) {
        const float* xsrc = xb + (size_t)ch * 2048 + (lt >> 4) * 64 + (lt & 15) * 4;
        float4 f = *(const float4*)xsrc;
        *(uint2*)(xs + (lt >> 4) * 64 + (lt & 15) * 4) =
            make_uint2(h2bits(pk2(f.x, f.y)), h2bits(pk2(f.z, f.w)));
      }
      __syncthreads();
      // pre2: dense computes u1 row 0
      if (!serialG) {
        float v = dense_row64(xs, ks, wfr);
        if (writerD) u1S[jcol] = f2hb(v + bj);
      }
      __syncthreads();
      // 32 slices: serial step s || dense u1 row s+1
      for (int g4 = 0; g4 < 4; ++g4) {
        u16 hreg0[8], hreg1[8];
        #pragma unroll
        for (int s8 = 0; s8 < 8; ++s8) {
          const int s = g4 * 8 + s8;
          if (serialG) {
            const int cu = s & 1, nx = cu ^ 1;
            float uv0 = hb2f(u1S[s * 272 + jc]);
            float uv1 = hb2f(u1S[s * 272 + jc + 16]);
            float v0, v1;
            mfma_step(hcH + cu * 320, oh, ol, wfr, v0, v1);
            u16 h0 = f2hb(fast_tanh(v0 + uv0));
            u16 h1 = f2hb(fast_tanh(v1 + uv1));
            if (l < 16) {
              hcH[nx * 320 + woff0] = h0;
              hcH[nx * 320 + woff0 + 20] = h1;
            }
            hreg0[s8] = h0;
            hreg1[s8] = h1;
            if (s8 == 7 && l < 16) {
              u16* d0 = hb + (size_t)(32 * ch + s - 7) * Hn + jc;
              #pragma unroll
              for (int i = 0; i < 8; ++i) {
                d0[i * Hn] = hreg0[i];
                d0[i * Hn + 16] = hreg1[i];
              }
            }
          } else if (s < 31) {
            float v = dense_row64(xs + (s + 1) * 64, ks, wfr);
            if (writerD) u1S[(s + 1) * 272 + jcol] = f2hb(v + bj);
          }
          __syncthreads();  // drains vmem (incl. h1 stores at s8==7)
        }
      }
      if (tid == 0)
        __hip_atomic_store(flags + b, ch + 1, __ATOMIC_RELEASE,
                           __HIP_MEMORY_SCOPE_AGENT);
    }
  } else {
    // ==================== ROLE BC ====================
    const int b = bid - Bn;
    const u16* hb1 = h1b16 + (size_t)b * Tn * Hn;
    u16* hsH = smemU;            // [32][320] halfs (h1 staging)
    u16* u2S = smemU + 10240;    // [32][272] halfs (u2)
    u16* hcU = smemU + 18944;    // 2 x 320 halfs (h2 state)
    const float bj = b2[jcol];   // dense bias
    u16* ldst = hsH + (lt >> 4) * 320 + 20 * (lt & 15);

    if (serialG)
      for (int i = tid; i < 640; i += 512) hcU[i] = 0;
    __syncthreads();

    for (int ch = 0; ch < 32; ++ch) {
      if (!serialG && lt == 0) {
        while (__hip_atomic_load(flags + b, __ATOMIC_ACQUIRE,
                                 __HIP_MEMORY_SCOPE_AGENT) < ch + 1)
          __builtin_amdgcn_s_sleep(8);
      }
      __syncthreads();  // flag acquired
      if (!serialG) {   // stage h1 chunk [32][256] -> hsH (slice layout)
        const uint4* src =
            (const uint4*)(hb1 + (size_t)(ch * 32 + (lt >> 4)) * Hn + 16 * (lt & 15));
        uint4 v0 = src[0], v1 = src[1];
        ((uint2*)ldst)[0] = make_uint2(v0.x, v0.y);
        ((uint2*)ldst)[1] = make_uint2(v0.z, v0.w);
        ((uint2*)ldst)[2] = make_uint2(v1.x, v1.y);
        ((uint2*)ldst)[3] = make_uint2(v1.z, v1.w);
      }
      __syncthreads();  // staged
      if (!serialG) {   // u2 row 0
        float v = dense_row256(hsH, ks, wfr);
        if (writerD) u2S[jcol] = f2hb(v + bj);
      }
      __syncthreads();  // row 0 visible

      for (int g4 = 0; g4 < 4; ++g4) {
        #pragma unroll
        for (int s8 = 0; s8 < 8; ++s8) {
          const int s = g4 * 8 + s8;
          if (serialG) {
            const int cu = s & 1, nx = cu ^ 1;
            float uv0 = hb2f(u2S[s * 272 + jc]);
            float uv1 = hb2f(u2S[s * 272 + jc + 16]);
            float v0, v1;
            mfma_step(hcU + cu * 320, oh, ol, wfr, v0, v1);
            if (l < 16) {
              hcU[nx * 320 + woff0] = f2hb(fast_tanh(v0 + uv0));
              hcU[nx * 320 + woff0 + 20] = f2hb(fast_tanh(v1 + uv1));
            }
          } else if (s < 31) {
            float v = dense_row256(hsH + (s + 1) * 320, ks, wfr);
            if (writerD) u2S[(s + 1) * 272 + jcol] = f2hb(v + bj);
          }
          __syncthreads();
        }
      }
    }
    if (tid < Hn)
      hfinal[(size_t)b * Hn + tid] = hb2f(hcU[(tid >> 4) * 20 + (tid & 15)]);
  }
}

// ---------------------------------------------------------------------------
// Head: out = softmax(h2_T @ Wd + bd). f32, unchanged.
// ---------------------------------------------------------------------------
__global__ __launch_bounds__(128) void head_kernel(
    const float* __restrict__ hfinal, const float* __restrict__ Wd,
    const float* __restrict__ bd, float* __restrict__ out) {
  __shared__ float hrow[Hn];
  __shared__ float red[On];
  const int o = threadIdx.x;
  const int b = blockIdx.x;
  hrow[o] = hfinal[(size_t)b * Hn + o];
  hrow[o + 128] = hfinal[(size_t)b * Hn + 128 + o];
  __syncthreads();
  float acc = bd[o];
  #pragma unroll 8
  for (int k = 0; k < Hn; ++k) acc = fmaf(hrow[k], Wd[(size_t)k * On + o], acc);
  red[o] = acc;
  __syncthreads();
  #pragma unroll
  for (int s = 64; s > 0; s >>= 1) {
    if (o < s) red[o] = fmaxf(red[o], red[o + s]);
    __syncthreads();
  }
  const float mx = red[0];
  __syncthreads();
  const float e = __expf(acc - mx);
  red[o] = e;
  __syncthreads();
  #pragma unroll
  for (int s = 64; s > 0; s >>= 1) {
    if (o < s) red[o] += red[o + s];
    __syncthreads();
  }
  out[(size_t)b * On + o] = e / red[0];
}

// ---------------------------------------------------------------------------
extern "C" void kernel_launch(void* const* d_in, const int* in_sizes, int n_in,
                              void* d_out, int out_size, void* d_ws, size_t ws_size,
                              hipStream_t stream) {
  const float* x   = (const float*)d_in[0];
  const float* Wx1 = (const float*)d_in[1];
  const float* Wh1 = (const float*)d_in[2];
  const float* b1  = (const float*)d_in[3];
  const float* Wx2 = (const float*)d_in[4];
  const float* Wh2 = (const float*)d_in[5];
  const float* b2  = (const float*)d_in[6];
  const float* Wd  = (const float*)d_in[7];
  const float* bd  = (const float*)d_in[8];
  float* out = (float*)d_out;

  u16* h1b16 = (u16*)d_ws;                            // [B,T,256] f16 (64 MB)
  float* hfinal = (float*)(h1b16 + (size_t)Bn * Tn * Hn);  // [B,256] f32
  int* flags = (int*)(hfinal + (size_t)Bn * Hn);      // [B] A->BC

  hipMemsetAsync(flags, 0, Bn * sizeof(int), stream);
  stage1_kernel<<<2 * Bn, 1024, 0, stream>>>(x, Wx1, Wh1, b1, Wx2, b2, Wh2,
                                             h1b16, flags, hfinal);
  head_kernel<<<Bn, 128, 0, stream>>>(hfinal, Wd, bd, out);
}